// Round 7
// baseline (146.251 us; speedup 1.0000x reference)
//
#include <hip/hip_runtime.h>

#define OUT_MU 131072
#define OUT_OM 262144
#define BIAS_OFF 4194304              // half-index of bias pack inside d_ws
#define WOUT_OFF 4210688              // half-index of packed W_out

typedef _Float16 half8 __attribute__((ext_vector_type(8)));
typedef _Float16 half4 __attribute__((ext_vector_type(4)));
typedef float    floatx16 __attribute__((ext_vector_type(16)));

__device__ __forceinline__ void wait_lgkm0() {
    asm volatile("s_waitcnt lgkmcnt(0)" ::: "memory");
}
__device__ __forceinline__ void wait_vm0() {
    asm volatile("s_waitcnt vmcnt(0)" ::: "memory");
}
__device__ __forceinline__ void barrier_raw() {
    asm volatile("s_barrier" ::: "memory");
}

#define AS1 __attribute__((address_space(1)))
#define AS3 __attribute__((address_space(3)))

// ---------------------------------------------------------------------------
// Repack hidden weights fp32 -> fp16 as 32x32x16 A-fragments:
//   [ch(4b)][l(2b)][ks(4b)][wv(2b)][nt(1b)][lane(6b)] half8 units.
// Lane l6 of wave wv holds, for (layer l, kstep ks, tile nt):
//   n = wv*64 + nt*32 + (l6&31), k = ks*16 + (l6>>5)*8 + e   (e=0..7)
// ---------------------------------------------------------------------------
__global__ void prep_w(const float* __restrict__ Wr_h,
                       const float* __restrict__ Wc_h,
                       _Float16* __restrict__ dst) {
    int v = blockIdx.x * 256 + threadIdx.x;        // 524288 half8 slots
    int lane = v & 63;
    int nt   = (v >> 6) & 1;
    int wv   = (v >> 7) & 3;
    int ks   = (v >> 9) & 15;
    int l    = (v >> 13) & 3;
    int ch   = v >> 15;
    int n  = wv * 64 + nt * 32 + (lane & 31);
    int k0 = ks * 16 + (lane >> 5) * 8;
    const float* src = (ch < 8) ? Wr_h : Wc_h;
    int c = ch & 7;
    const float* p = src + ((size_t)((l * 8 + c) * 256 + n)) * 256 + k0;
    float4 a = *(const float4*)p;
    float4 b = *(const float4*)(p + 4);
    half8 o;
    o[0] = (_Float16)a.x; o[1] = (_Float16)a.y; o[2] = (_Float16)a.z; o[3] = (_Float16)a.w;
    o[4] = (_Float16)b.x; o[5] = (_Float16)b.y; o[6] = (_Float16)b.z; o[7] = (_Float16)b.w;
    *(half8*)(dst + (size_t)v * 8) = o;
}

// Bias pack: [ch(4b)][l(2b)][wv(2b)][hi(1b)][nt(1b)][q(2b)][e(2b)] halves.
// n = wv*64 + nt*32 + q*8 + hi*4 + e.
__global__ void prep_b(const float* __restrict__ br_h,
                       const float* __restrict__ bc_h,
                       _Float16* __restrict__ dst) {
    int t = blockIdx.x * 256 + threadIdx.x;        // 16384
    int e  = t & 3;
    int q  = (t >> 2) & 3;
    int nt = (t >> 4) & 1;
    int hi = (t >> 5) & 1;
    int wv = (t >> 6) & 3;
    int l  = (t >> 8) & 3;
    int ch = (t >> 10) & 15;
    int n = wv * 64 + nt * 32 + q * 8 + hi * 4 + e;
    const float* src = (ch < 8) ? br_h : bc_h;
    dst[BIAS_OFF + t] = (_Float16)src[(l * 8 + (ch & 7)) * 256 + n];
}

// W_out pack: [ch(16)][d(2)][j(256)] fp16 (real channels use d=0 only).
__global__ void prep_wo(const float* __restrict__ Wr_out,
                        const float* __restrict__ Wc_out,
                        _Float16* __restrict__ dst) {
    int t = blockIdx.x * 256 + threadIdx.x;        // 8192
    int j = t & 255, d = (t >> 8) & 1, ch = t >> 9;
    int c = ch & 7;
    float v;
    if (ch < 8) v = d ? 0.f : Wr_out[c * 256 + j];
    else        v = Wc_out[(c * 2 + d) * 256 + j];
    dst[WOUT_OFF + t] = (_Float16)v;
}

// ---------------------------------------------------------------------------
// Fused MLP, 32x32x16_f16. Block = (ch = bid&15, 128 rows). h (128x256 fp16,
// swizzled, 64 KB) in LDS across layers; z-tile (12 KB) staged via
// global_load_lds (wave-private rows -> no barrier). Weights global->VGPR
// (lane-exact fragments, register dbuf). K-loop: NO barriers; 2/layer edge.
// Wave wv owns n in [wv*64, +64) = 2 tiles, all 128 m = 4 tiles.
// D layout (32x32): col m = lane&31, row n_local = (r&3) + 8*(r>>2) + 4*(lane>>5).
// ---------------------------------------------------------------------------
__global__ __launch_bounds__(256, 2)
void mlp_fused(const float* __restrict__ z,
               const float* __restrict__ Wr_in, const float* __restrict__ br_in,
               const float* __restrict__ Wc_in, const float* __restrict__ bc_in,
               const float* __restrict__ br_out, const float* __restrict__ bc_out,
               const _Float16* __restrict__ wst,
               float* __restrict__ out) {
    __shared__ __align__(16) char smem[77824];     // [0,64K)=h, [64K,76K)=z
    const int tid  = threadIdx.x;
    const int lane = tid & 63;
    const int wv   = tid >> 6;
    const int bid  = blockIdx.x;
    const int ch   = bid & 15;
    const int m0   = (bid >> 4) * 128;
    const bool isC = ch >= 8;
    const int c    = ch & 7;
    const int hi   = lane >> 5;
    const int r32  = lane & 31;
    float* zbuf = (float*)(smem + 65536);

    // ---- stage z tile (wave wv stages+consumes rows [wv*32, wv*32+32)) ----
    {
        const float* zs = z + (size_t)m0 * 24 + wv * 768 + lane * 4;
        char* zd = smem + 65536 + wv * 3072;
        __builtin_amdgcn_global_load_lds((const AS1 void*)zs,         (AS3 void*)zd,          16, 0, 0);
        __builtin_amdgcn_global_load_lds((const AS1 void*)(zs + 256), (AS3 void*)(zd + 1024), 16, 0, 0);
        __builtin_amdgcn_global_load_lds((const AS1 void*)(zs + 512), (AS3 void*)(zd + 2048), 16, 0, 0);
    }

    // weight fragments: wl[ks*512 + nt*64] is this lane's half8 for (ks, nt)
    const half8* wl = (const half8*)wst + (size_t)ch * 32768 + wv * 128 + lane;

    half8 wr[2][2];
    #pragma unroll
    for (int nt = 0; nt < 2; ++nt) wr[0][nt] = wl[nt * 64];   // (l=0, ks=0)

    // B-frag bases: addr(mt, ks) = vb[mt] ^ (ks<<5)
    int vb[4];
    #pragma unroll
    for (int mt = 0; mt < 4; ++mt)
        vb[mt] = (mt * 32 + r32) * 512 + ((hi ^ (lane & 7)) << 4);

    // input-layer weights (registers)
    const int jg = tid & 31;                       // slot j0 = jg*8
    const int rg = tid >> 5;                       // rows rg*16 .. rg*16+15
    const float* Wi = (isC ? Wc_in : Wr_in) + c * 256 + jg * 8;
    const float* bi = (isC ? bc_in : br_in) + c * 256 + jg * 8;
    float4 w0 = *(const float4*)Wi;
    float4 w1 = *(const float4*)(Wi + 4);
    float4 v0 = *(const float4*)bi;
    float4 v1 = *(const float4*)(bi + 4);

    wait_vm0();                                     // z tile + wr[0] + Wi/bi landed

    // ---- input layer: h0[m][j] = relu(x_m * W_in[j] + b_in[j]) ----
    {
        #pragma unroll
        for (int i = 0; i < 16; ++i) {
            int m = rg * 16 + i;
            float x;
            if (!isC) x = zbuf[m * 24 + c];
            else {
                float2 p = *(const float2*)(zbuf + m * 24 + 8 + 2 * c);
                x = p.x * p.x + p.y * p.y;
            }
            half8 o;
            o[0] = (_Float16)fmaxf(fmaf(x, w0.x, v0.x), 0.f);
            o[1] = (_Float16)fmaxf(fmaf(x, w0.y, v0.y), 0.f);
            o[2] = (_Float16)fmaxf(fmaf(x, w0.z, v0.z), 0.f);
            o[3] = (_Float16)fmaxf(fmaf(x, w0.w, v0.w), 0.f);
            o[4] = (_Float16)fmaxf(fmaf(x, w1.x, v1.x), 0.f);
            o[5] = (_Float16)fmaxf(fmaf(x, w1.y, v1.y), 0.f);
            o[6] = (_Float16)fmaxf(fmaf(x, w1.z, v1.z), 0.f);
            o[7] = (_Float16)fmaxf(fmaf(x, w1.w, v1.w), 0.f);
            *(half8*)(smem + m * 512 + ((jg ^ (m & 7)) << 4)) = o;
        }
    }
    wait_lgkm0();
    barrier_raw();                                  // h0 visible

    const half8* bpc = (const half8*)(wst + BIAS_OFF) + ((ch * 4) * 4 + wv) * 8 + hi * 4;

    #pragma unroll 1
    for (int l = 0; l < 4; ++l) {
        // bias for this layer: 4 half8 ([nt(2)][qpair(2)] of [q&1(2)][e(4)])
        const half8* bl = bpc + l * 32;             // l stride: 4wv*2hi*4 = 32 half8
        half8 bb0 = bl[0], bb1 = bl[1], bb2 = bl[2], bb3 = bl[3];

        floatx16 acc[2][4];
        #pragma unroll
        for (int a = 0; a < 2; ++a)
            #pragma unroll
            for (int b = 0; b < 4; ++b) acc[a][b] = 0.f;

        half8 bfr[2][4];
        #pragma unroll
        for (int mt = 0; mt < 4; ++mt)              // ks = 0 prologue
            bfr[0][mt] = *(const half8*)(smem + vb[mt]);

        #pragma unroll
        for (int ks = 0; ks < 16; ++ks) {
            {   // weight prefetch for ks+1 (ks=15 -> next layer's ks=0; for
                // l=3 reads ch+1 / bias region: allocated, harmless)
                const half8* p = wl + (ks + 1) * 512;
                wr[(ks + 1) & 1][0] = p[0];
                wr[(ks + 1) & 1][1] = p[64];
            }
            if (ks < 15) {                          // activation prefetch
                #pragma unroll
                for (int mt = 0; mt < 4; ++mt)
                    bfr[(ks + 1) & 1][mt] =
                        *(const half8*)(smem + (vb[mt] ^ ((ks + 1) << 5)));
            }
            __builtin_amdgcn_s_setprio(1);
            #pragma unroll
            for (int nt = 0; nt < 2; ++nt)
                #pragma unroll
                for (int mt = 0; mt < 4; ++mt)
                    acc[nt][mt] = __builtin_amdgcn_mfma_f32_32x32x16_f16(
                        wr[ks & 1][nt], bfr[ks & 1][mt], acc[nt][mt], 0, 0, 0);
            __builtin_amdgcn_s_setprio(0);
        }
        wl += 8192;                                 // next layer's weights

        // ---- layer epilogue: bias + relu -> h (in place) ----
        wait_lgkm0();
        barrier_raw();                              // all reads of layer l done
        #pragma unroll
        for (int nt = 0; nt < 2; ++nt) {
            #pragma unroll
            for (int q = 0; q < 4; ++q) {
                half8 bv = (nt * 2 + (q >> 1)) == 0 ? bb0 :
                           (nt * 2 + (q >> 1)) == 1 ? bb1 :
                           (nt * 2 + (q >> 1)) == 2 ? bb2 : bb3;
                const int be = (q & 1) * 4;
                float b0 = (float)bv[be + 0];
                float b1 = (float)bv[be + 1];
                float b2 = (float)bv[be + 2];
                float b3 = (float)bv[be + 3];
                const int slot = wv * 8 + nt * 4 + q;
                #pragma unroll
                for (int mt = 0; mt < 4; ++mt) {
                    const int m = mt * 32 + r32;
                    half4 o;
                    o[0] = (_Float16)fmaxf(acc[nt][mt][4 * q + 0] + b0, 0.f);
                    o[1] = (_Float16)fmaxf(acc[nt][mt][4 * q + 1] + b1, 0.f);
                    o[2] = (_Float16)fmaxf(acc[nt][mt][4 * q + 2] + b2, 0.f);
                    o[3] = (_Float16)fmaxf(acc[nt][mt][4 * q + 3] + b3, 0.f);
                    *(half4*)(smem + m * 512 + ((slot ^ (m & 7)) << 4) + hi * 8) = o;
                }
            }
        }
        wait_lgkm0();
        barrier_raw();                              // new h visible
    }

    // ---- output layer: 2 threads/row, fp16 packed W_out ----
    {
        const int q = tid & 1, m = tid >> 1;       // m in 0..127
        const half8* Wo = (const half8*)(wst + WOUT_OFF) + ch * 64 + q * 16;
        float s0 = 0.f, s1 = 0.f;
        #pragma unroll
        for (int i = 0; i < 16; ++i) {
            int slot = q * 16 + i;
            half8 hv = *(const half8*)(smem + m * 512 + ((slot ^ (m & 7)) << 4));
            half8 wo0 = Wo[i];
            #pragma unroll
            for (int e = 0; e < 8; ++e) s0 = fmaf((float)hv[e], (float)wo0[e], s0);
            if (isC) {
                half8 wo1 = Wo[32 + i];
                #pragma unroll
                for (int e = 0; e < 8; ++e) s1 = fmaf((float)hv[e], (float)wo1[e], s1);
            }
        }
        s0 += __shfl_xor(s0, 1);
        if (isC) s1 += __shfl_xor(s1, 1);
        if (q == 0) {
            const int row = m0 + m;
            if (!isC) {
                out[row * 8 + c] = s0 + br_out[c];
            } else {
                out[OUT_MU + row * 8 + c] = s0 + bc_out[c * 2];
                out[OUT_OM + row * 8 + c] = s1 + bc_out[c * 2 + 1];
            }
        }
    }
}

extern "C" void kernel_launch(void* const* d_in, const int* in_sizes, int n_in,
                              void* d_out, int out_size, void* d_ws, size_t ws_size,
                              hipStream_t stream) {
    const float* z      = (const float*)d_in[0];
    const float* Wr_in  = (const float*)d_in[1];
    const float* br_in  = (const float*)d_in[2];
    const float* Wr_h   = (const float*)d_in[3];
    const float* br_h   = (const float*)d_in[4];
    const float* Wr_out = (const float*)d_in[5];
    const float* br_out = (const float*)d_in[6];
    const float* Wc_in  = (const float*)d_in[7];
    const float* bc_in  = (const float*)d_in[8];
    const float* Wc_h   = (const float*)d_in[9];
    const float* bc_h   = (const float*)d_in[10];
    const float* Wc_out = (const float*)d_in[11];
    const float* bc_out = (const float*)d_in[12];
    _Float16* wst = (_Float16*)d_ws;               // 8 MB weights + bias + wout packs
    float* out = (float*)d_out;

    prep_w<<<2048, 256, 0, stream>>>(Wr_h, Wc_h, wst);
    prep_b<<<64, 256, 0, stream>>>(br_h, bc_h, wst);
    prep_wo<<<32, 256, 0, stream>>>(Wr_out, Wc_out, wst);
    mlp_fused<<<2048, 256, 0, stream>>>(z, Wr_in, br_in, Wc_in, bc_in,
                                        br_out, bc_out, wst, out);
}